// Round 3
// baseline (388.626 us; speedup 1.0000x reference)
//
#include <hip/hip_runtime.h>
#include <cstdint>
#include <cstdlib>
#include <vector>

#define RW_VOCAB 512
#define RW_T 64
#define RW_D 32
#define RW_NNODES 4000
#define RW_NIN 2048      // T*D
#define RW_NBIAS 2
#define RW_NDST 1950     // hidden(1438) + vocab(512)
#define RW_BATCH 512
#define RW_NLAYERS 6

// ---------------------------------------------------------------------------
// Host-side replication of np.random.RandomState(0) graph construction.
// RandomState(int_seed) -> mt19937_seed (init_genrand variant); random_sample
// -> ((a>>5)*2^26 + (b>>6)) / 2^53 consuming two uint32 draws per double.
// Empty-column repair (rng.randint) triggers with prob ~0.97^2050 ~= 7e-28:
// never, so the stream is exactly start*size doubles per layer, row-major,
// matching np.nonzero edge order (sorted by src then dst).
// ---------------------------------------------------------------------------
namespace {

struct MT19937 {
  uint32_t mt[624];
  int mti;
  void seed(uint32_t s) {
    for (int i = 0; i < 624; ++i) {
      mt[i] = s;
      s = 1812433253u * (s ^ (s >> 30)) + (uint32_t)i + 1u;
    }
    mti = 624;
  }
  inline uint32_t next() {
    if (mti >= 624) {
      for (int i = 0; i < 624; ++i) {
        uint32_t y = (mt[i] & 0x80000000u) | (mt[(i + 1) % 624] & 0x7fffffffu);
        mt[i] = mt[(i + 397) % 624] ^ (y >> 1) ^ ((y & 1u) ? 2567483615u : 0u);
      }
      mti = 0;
    }
    uint32_t y = mt[mti++];
    y ^= y >> 11;
    y ^= (y << 7) & 2636928640u;
    y ^= (y << 15) & 4022730752u;
    y ^= y >> 18;
    return y;
  }
  inline double rnd() {
    uint32_t a = next() >> 5, b = next() >> 6;
    return ((double)a * 67108864.0 + (double)b) / 9007199254740992.0;
  }
};

const int LAYER_SIZES[RW_NLAYERS] = {288, 288, 288, 287, 287, 512};

struct HostGraph {
  int E;
  uint32_t* h_buf;     // [packed edges E][row_ptr RW_NDST+1]
  size_t buf_bytes;
};

HostGraph* build_host_graph() {
  HostGraph* G = new HostGraph();
  MT19937 mt;
  mt.seed(0);
  // rows[d] = packed (widx<<12)|src for destination node d (global dst index)
  std::vector<std::vector<uint32_t>> rows(RW_NDST);
  int start = RW_NIN + RW_NBIAS;  // 2050
  int dstbase = 0;
  uint32_t widx = 0;
  for (int li = 0; li < RW_NLAYERS; ++li) {
    const int size = LAYER_SIZES[li];
    for (int u = 0; u < start; ++u) {
      for (int v = 0; v < size; ++v) {
        if (mt.rnd() < 0.03) {
          rows[dstbase + v].push_back((widx << 12) | (uint32_t)u);
          ++widx;
        }
      }
    }
    dstbase += size;
    start += size;
  }
  const int E = (int)widx;
  G->E = E;
  G->buf_bytes = ((size_t)E + RW_NDST + 1) * 4;
  if (hipHostMalloc((void**)&G->h_buf, G->buf_bytes) != hipSuccess) {
    G->h_buf = (uint32_t*)malloc(G->buf_bytes);
  }
  uint32_t* pe = G->h_buf;
  uint32_t* rp = G->h_buf + E;
  uint32_t acc = 0;
  for (int r = 0; r < RW_NDST; ++r) {
    rp[r] = acc;
    for (uint32_t p : rows[r]) pe[acc++] = p;  // per-dst in increasing src order
  }
  rp[RW_NDST] = acc;
  return G;
}

}  // namespace

// ---------------------------------------------------------------------------
// Kernels
// ---------------------------------------------------------------------------

// Reorder weights into CSR edge order so the hot loop streams contiguously.
__global__ void rwnn_gather_w(const uint32_t* __restrict__ pe,
                              const float* __restrict__ w,
                              float* __restrict__ wcsr, int E) {
  int i = blockIdx.x * blockDim.x + threadIdx.x;
  if (i < E) wcsr[i] = w[pe[i] >> 12];
}

// One block per batch row; the full 4000-node activation slab lives in LDS.
template <bool GATHERED>
__global__ __launch_bounds__(256) void rwnn_fwd(
    const int* __restrict__ ids, const float* __restrict__ tok,
    const float* __restrict__ pos, const int* __restrict__ rp,
    const uint32_t* __restrict__ pe, const float* __restrict__ wv,
    float* __restrict__ out) {
  __shared__ float vals[RW_NNODES];
  const int b = blockIdx.x;

  // Embedding: vals[t*32+d] = tok[id[t]*32+d] + pos[t*32+d]; bias nodes = 1.
  for (int i = threadIdx.x; i < RW_NIN; i += 256) {
    const int t = i >> 5;
    const int d = i & 31;
    const int id = ids[b * RW_T + t];
    vals[i] = tok[(id << 5) + d] + pos[i];
  }
  if (threadIdx.x < RW_NBIAS) vals[RW_NIN + threadIdx.x] = 1.0f;
  __syncthreads();

  const int sizes[RW_NLAYERS] = {288, 288, 288, 287, 287, 512};
  int node_base = RW_NIN + RW_NBIAS;
  int dst_base = 0;
  for (int li = 0; li < RW_NLAYERS; ++li) {
    const int size = sizes[li];
    const bool last = (li == RW_NLAYERS - 1);
    for (int v = threadIdx.x; v < size; v += 256) {
      const int r0 = rp[dst_base + v];
      const int r1 = rp[dst_base + v + 1];
      float a0 = 0.0f, a1 = 0.0f;
      int e = r0;
      for (; e + 2 <= r1; e += 2) {
        const uint32_t p0 = pe[e];
        const uint32_t p1 = pe[e + 1];
        const float w0 = GATHERED ? wv[e] : wv[p0 >> 12];
        const float w1 = GATHERED ? wv[e + 1] : wv[p1 >> 12];
        a0 = fmaf(vals[p0 & 0xFFFu], w0, a0);
        a1 = fmaf(vals[p1 & 0xFFFu], w1, a1);
      }
      if (e < r1) {
        const uint32_t p = pe[e];
        a0 = fmaf(vals[p & 0xFFFu], GATHERED ? wv[e] : wv[p >> 12], a0);
      }
      const float acc = a0 + a1;
      if (last) {
        out[b * RW_VOCAB + v] = acc;  // final layer: no tanh, straight to out
      } else {
        vals[node_base + v] = tanhf(acc);
      }
    }
    __syncthreads();
    node_base += size;
    dst_base += size;
  }
}

// ---------------------------------------------------------------------------
// Launch
// ---------------------------------------------------------------------------
extern "C" void kernel_launch(void* const* d_in, const int* in_sizes, int n_in,
                              void* d_out, int out_size, void* d_ws,
                              size_t ws_size, hipStream_t stream) {
  static HostGraph* G = build_host_graph();  // host-only one-time init
  const int E = G->E;

  const int* ids = (const int*)d_in[0];
  const float* tok = (const float*)d_in[1];
  const float* pos = (const float*)d_in[2];
  const float* w = (const float*)d_in[3];
  float* out = (float*)d_out;

  char* ws = (char*)d_ws;
  uint32_t* d_pe = (uint32_t*)ws;
  int* d_rp = (int*)(ws + (size_t)E * 4);
  float* d_wcsr = (float*)(ws + ((size_t)E + RW_NDST + 1) * 4);
  const size_t need_gather = ((size_t)2 * E + RW_NDST + 1) * 4;
  const bool use_gather = (ws_size >= need_gather);

  // Graph topology upload (d_ws is re-poisoned before every call).
  hipMemcpyAsync(ws, G->h_buf, G->buf_bytes, hipMemcpyHostToDevice, stream);

  if (use_gather) {
    rwnn_gather_w<<<(E + 255) / 256, 256, 0, stream>>>(d_pe, w, d_wcsr, E);
    rwnn_fwd<true><<<RW_BATCH, 256, 0, stream>>>(ids, tok, pos, d_rp, d_pe,
                                                 d_wcsr, out);
  } else {
    rwnn_fwd<false><<<RW_BATCH, 256, 0, stream>>>(ids, tok, pos, d_rp, d_pe, w,
                                                  out);
  }
}